// Round 2
// baseline (90.011 us; speedup 1.0000x reference)
//
#include <hip/hip_runtime.h>

#define NPTS 96
#define HID  64
#define RANK 32

typedef float f2 __attribute__((ext_vector_type(2)));
typedef float f4 __attribute__((ext_vector_type(4)));

// -------- Kernel 1: the 4 tiny MLPs -> factor matrices in ws --------
// plain[axis][f][n]  at ws + axis*RANK*NPTS + f*NPTS + n
// trans[axis][n][f]  at ws + 4*RANK*NPTS + (axis*NPTS + n)*RANK + f
__global__ __launch_bounds__(64) void spinn_mlp(
    const float* __restrict__ t, const float* __restrict__ x,
    const float* __restrict__ y, const float* __restrict__ z,
    const float* __restrict__ W1, const float* __restrict__ b1,
    const float* __restrict__ W2, const float* __restrict__ b2,
    const float* __restrict__ W3, const float* __restrict__ b3,
    float* __restrict__ ws)
{
    const int n    = blockIdx.x;   // point 0..95
    const int axis = blockIdx.y;   // 0..3
    const int j    = threadIdx.x;  // 0..63

    const float* coords[4] = { t, x, y, z };
    const float c = coords[axis][n];

    __shared__ float h1[HID];
    __shared__ float h2[HID];

    // layer 1: [1] -> [64]
    h1[j] = tanhf(fmaf(c, W1[axis * HID + j], b1[axis * HID + j]));
    __syncthreads();

    // layer 2: [64] -> [64]
    float a = b2[axis * HID + j];
    #pragma unroll
    for (int k = 0; k < HID; ++k)
        a = fmaf(h1[k], W2[(axis * HID + k) * HID + j], a);
    h2[j] = tanhf(a);
    __syncthreads();

    // layer 3: [64] -> [32]
    if (j < RANK) {
        float o = b3[axis * RANK + j];
        #pragma unroll
        for (int k = 0; k < HID; ++k)
            o = fmaf(h2[k], W3[(axis * HID + k) * RANK + j], o);
        ws[axis * RANK * NPTS + j * NPTS + n]             = o; // plain [axis][f][n]
        ws[4 * RANK * NPTS + (axis * NPTS + n) * RANK + j] = o; // trans [axis][n][f]
    }
}

// -------- Kernel 2: rank-32 CP reconstruction, 96^4 fp32 output --------
// Thread owns (y, 4 consecutive z) with q[f] = ft[f,t]*fy[f,y]*fz[f,z0..3]
// register-resident; loops over 48 x values, per step only fx[.,x] (32 floats,
// block-uniform address -> scalar loads) is consumed.
__global__ __launch_bounds__(192) void spinn_outer(
    const float* __restrict__ ws, float* __restrict__ out)
{
    const float* plain = ws;
    const float* trans = ws + 4 * RANK * NPTS;

    const int tt  = blockIdx.x;        // t: 0..95
    const int yb  = blockIdx.y;        // y block: 0..11
    const int xh  = blockIdx.z;        // x half: 0..1
    const int tid = threadIdx.x;       // 0..191
    const int yq  = tid / 24;          // 0..7
    const int z4  = tid % 24;          // 0..23
    const int yy  = yb * 8 + yq;
    const int z0  = z4 * 4;

    const float* ftT = trans + (0 * NPTS + tt) * RANK;  // 32 contiguous
    const float* fyT = trans + (2 * NPTS + yy) * RANK;  // 32 contiguous
    const float* fzP = plain + 3 * RANK * NPTS;          // fz[f][n]

    // q[f] = ft[f]*fy[f]*fz[f][z0..z0+3], kept in 128 VGPRs
    f2 q0[RANK], q1[RANK];
    #pragma unroll
    for (int f = 0; f < RANK; ++f) {
        const float g = ftT[f] * fyT[f];
        const float* fzf = fzP + f * NPTS + z0;
        f2 a = { fzf[0], fzf[1] };
        f2 b = { fzf[2], fzf[3] };
        q0[f] = a * g;
        q1[f] = b * g;
    }

    const float* fxT = trans + 1 * NPTS * RANK;          // [x][f]
    const int x0 = xh * 48;
    const size_t outb = (size_t)tt * NPTS * NPTS * NPTS + (size_t)yy * NPTS + z0;

    for (int xs = 0; xs < 48; ++xs) {
        const int xx = x0 + xs;
        const float* __restrict__ fx = fxT + xx * RANK;  // block-uniform addr
        f2 acc0 = { 0.f, 0.f }, acc1 = { 0.f, 0.f };
        #pragma unroll
        for (int f = 0; f < RANK; ++f) {
            const float s = fx[f];
            const f2 s2 = { s, s };
            acc0 = __builtin_elementwise_fma(s2, q0[f], acc0);
            acc1 = __builtin_elementwise_fma(s2, q1[f], acc1);
        }
        f4 res = { acc0.x, acc0.y, acc1.x, acc1.y };
        f4* dst = (f4*)(out + outb + (size_t)xx * NPTS * NPTS);
        __builtin_nontemporal_store(res, dst);
    }
}

extern "C" void kernel_launch(void* const* d_in, const int* in_sizes, int n_in,
                              void* d_out, int out_size, void* d_ws, size_t ws_size,
                              hipStream_t stream)
{
    const float* t  = (const float*)d_in[0];
    const float* x  = (const float*)d_in[1];
    const float* y  = (const float*)d_in[2];
    const float* z  = (const float*)d_in[3];
    const float* W1 = (const float*)d_in[4];
    const float* b1 = (const float*)d_in[5];
    const float* W2 = (const float*)d_in[6];
    const float* b2 = (const float*)d_in[7];
    const float* W3 = (const float*)d_in[8];
    const float* b3 = (const float*)d_in[9];

    float* ws  = (float*)d_ws;
    float* out = (float*)d_out;

    // Stage 1: factors (4 axes x 96 points), ~negligible
    spinn_mlp<<<dim3(NPTS, 4), 64, 0, stream>>>(t, x, y, z, W1, b1, W2, b2, W3, b3, ws);

    // Stage 2: 96^4 reconstruction; grid 96 t x 12 y-blocks x 2 x-halves = 2304 blocks
    spinn_outer<<<dim3(NPTS, 12, 2), 192, 0, stream>>>(ws, out);
}